// Round 7
// baseline (111.364 us; speedup 1.0000x reference)
//
#include <hip/hip_runtime.h>
#include <hip/hip_bf16.h>
#include <math.h>

#define DEVI __device__ __forceinline__

typedef __attribute__((ext_vector_type(4))) float f32x4;
typedef __attribute__((ext_vector_type(8))) short bf16x8;

DEVI unsigned short f2bf(float f) {
  union { float f; unsigned int u; } v; v.f = f;
  return (unsigned short)((v.u + 0x7FFFu + ((v.u >> 16) & 1u)) >> 16);
}
DEVI float bf2f(unsigned short s) {
  union { unsigned int u; float f; } v; v.u = ((unsigned int)s) << 16; return v.f;
}
DEVI bf16x8 pack8(f32x4 a, f32x4 b) {
  bf16x8 r;
  r[0] = (short)f2bf(a[0]); r[1] = (short)f2bf(a[1]);
  r[2] = (short)f2bf(a[2]); r[3] = (short)f2bf(a[3]);
  r[4] = (short)f2bf(b[0]); r[5] = (short)f2bf(b[1]);
  r[6] = (short)f2bf(b[2]); r[7] = (short)f2bf(b[3]);
  return r;
}
DEVI void gload16(const unsigned short* g, unsigned short* l) {
  __builtin_amdgcn_global_load_lds(
      (const __attribute__((address_space(1))) unsigned int*)g,
      (__attribute__((address_space(3))) unsigned int*)l, 16, 0, 0);
}
// raw workgroup barrier WITHOUT the implicit vmcnt(0) drain of __syncthreads
#define SBAR() do { asm volatile("" ::: "memory"); \
                    __builtin_amdgcn_s_barrier();  \
                    asm volatile("" ::: "memory"); } while (0)

// ==== prep: weights f32[K][512] -> bf16 [512][K] swz ; acts f32[M][K] -> bf16 [M][K] swz
// swizzle: within each 64-elem k-group, kblock kb of row n stored at ((kb+n)&7).
struct PrepJobs {
  const float* src[9];
  unsigned short* dst[9];
  int K[9];
  int base[9];
  int type[9];   // 0 = weight transpose (64x64 tiles), 1 = activation convert
};

__global__ __launch_bounds__(256) void prep(PrepJobs J) {
  __shared__ float t[64][65];   // 16.6 KB
  int tile = blockIdx.x;
  int job = 0;
  while (job < 8 && tile >= J.base[job + 1]) ++job;
  int tl = tile - J.base[job];
  int K = J.K[job];
  if (J.type[job] == 0) {
    int tn = tl & 7, tk = tl >> 3;   // 512/64 = 8 n-tiles
    int x = threadIdx.x & 63, y = threadIdx.x >> 6;
    const float* s = J.src[job];
    int k0 = tk * 64, n0 = tn * 64;
#pragma unroll
    for (int yy = y; yy < 64; yy += 4)
      t[yy][x] = s[(size_t)(k0 + yy) * 512 + n0 + x];
    __syncthreads();
    unsigned short* d = J.dst[job];
    int kb = (x >> 3) & 7, ko = x & 7;   // k = k0 + x, k0 % 64 == 0
#pragma unroll
    for (int yy = y; yy < 64; yy += 4) {
      int n = n0 + yy;
      int kswz = k0 + (((kb + n) & 7) << 3) + ko;
      d[(size_t)n * K + kswz] = f2bf(t[x][yy]);
    }
  } else {
    int nk = K >> 6;
    int rt = tl / nk;
    int r0 = rt * 64, k0 = (tl - rt * nk) * 64;
    int r = threadIdx.x >> 2, kq = threadIdx.x & 3;
    int row = r0 + r;
    const float* s = J.src[job] + (size_t)row * K + k0 + kq * 16;
    f32x4 a0 = *(const f32x4*)s;
    f32x4 a1 = *(const f32x4*)(s + 4);
    f32x4 a2 = *(const f32x4*)(s + 8);
    f32x4 a3 = *(const f32x4*)(s + 12);
    unsigned short* d = J.dst[job] + (size_t)row * K + k0;
    int kb0 = kq * 2;
    *(bf16x8*)(d + ((kb0 + row) & 7) * 8) = pack8(a0, a1);
    *(bf16x8*)(d + ((kb0 + 1 + row) & 7) * 8) = pack8(a2, a3);
  }
}

// ==== MFMA GEMM, counted-vmcnt double-buffer, templated tile ===============
// BM = MI*32, BN = NI*32, BK = 64; 4 waves (2 m x 2 n), wave tile (MI*16)x(NI*16).
// C[M][512] = concat(A0|A1|A2) @ B + bias. A/B bf16 pre-swizzled; staging is
// pure global_load_lds DMA; s_waitcnt vmcnt(MI+NI) keeps next tile in flight.
struct GJob {
  const unsigned short* A0; const unsigned short* A1; const unsigned short* A2;
  const unsigned short* Bt;
  const float* bias;
  unsigned short* Cb;
  float* Cf;
  int Astride, Ktot, lgSteps, tileBase;
};
struct GBatch { GJob j[5]; int njobs; };

template <int MI, int NI>
__global__ __launch_bounds__(256) void gemm_pipe(GBatch batch) {
  constexpr int BM = MI * 32, BN = NI * 32;
  constexpr int NT = 512 / BN;            // n-tiles per job
  // XCD-aware swizzle (grids divisible by 8)
  int cpx = gridDim.x >> 3;
  int gt = (blockIdx.x & 7) * cpx + (blockIdx.x >> 3);
  int job = 0;
#pragma unroll
  for (int i = 1; i < 5; ++i)
    if (i < batch.njobs && gt >= batch.j[i].tileBase) job = i;
  GJob J = batch.j[job];
  int tl = gt - J.tileBase;
  int bm = (tl / NT) * BM, bn = (tl % NT) * BN;

  __shared__ __align__(16) unsigned short La[2][BM * 64];
  __shared__ __align__(16) unsigned short Lb[2][BN * 64];

  int tid = threadIdx.x;
  int wave = tid >> 6, lane = tid & 63;
  int lrow = lane & 15, lq = lane >> 4;
  int wr = (wave >> 1) * (MI * 16), wc = (wave & 1) * (NI * 16);
  f32x4 acc[MI][NI] = {};

  int kmask = (1 << J.lgSteps) - 1;
  int nt = J.Ktot >> 6;

  auto stage_both = [&](int t, int buf) {
    int seg = t >> J.lgSteps;
    const unsigned short* Ab = (seg == 0) ? J.A0 : ((seg == 1) ? J.A1 : J.A2);
    const unsigned short* GA = Ab + (size_t)bm * J.Astride + (size_t)((t & kmask) << 6);
    const unsigned short* GB = J.Bt + (size_t)bn * J.Ktot + (size_t)t * 64;
#pragma unroll
    for (int p = 0; p < MI; ++p) {     // A: BM*64 bf16 = MI*256 slots of 16B
      int s = p * 256 + tid;
      gload16(GA + (size_t)(s >> 3) * J.Astride + (s & 7) * 8,
              &La[buf][(size_t)(p * 256 + wave * 64) * 8]);
    }
#pragma unroll
    for (int p = 0; p < NI; ++p) {     // B: BN*64 bf16 = NI*256 slots
      int s = p * 256 + tid;
      gload16(GB + (size_t)(s >> 3) * J.Ktot + (s & 7) * 8,
              &Lb[buf][(size_t)(p * 256 + wave * 64) * 8]);
    }
  };

  stage_both(0, 0);
  if (nt > 1) stage_both(1, 1);

  for (int t = 0; t < nt; ++t) {
    // wait until THIS tile's DMA landed; next tile's (MI+NI) stay in flight
    if (t + 1 < nt) {
      if constexpr (MI + NI == 8)      asm volatile("s_waitcnt vmcnt(8)" ::: "memory");
      else if constexpr (MI + NI == 6) asm volatile("s_waitcnt vmcnt(6)" ::: "memory");
      else                             asm volatile("s_waitcnt vmcnt(4)" ::: "memory");
    } else {
      asm volatile("s_waitcnt vmcnt(0)" ::: "memory");
    }
    SBAR();                              // all waves' tile-t data visible
    int cur = t & 1;
#pragma unroll
    for (int kc = 0; kc < 2; ++kc) {
      int kb = kc * 4 + lq;
      bf16x8 af[MI], bv[NI];
#pragma unroll
      for (int mi = 0; mi < MI; ++mi) {
        int r = wr + mi * 16 + lrow;
        af[mi] = *(const bf16x8*)&La[cur][r * 64 + ((kb + r) & 7) * 8];
      }
#pragma unroll
      for (int ni = 0; ni < NI; ++ni) {
        int r = wc + ni * 16 + lrow;
        bv[ni] = *(const bf16x8*)&Lb[cur][r * 64 + ((kb + r) & 7) * 8];
      }
#pragma unroll
      for (int mi = 0; mi < MI; ++mi)
#pragma unroll
        for (int ni = 0; ni < NI; ++ni)
          acc[mi][ni] = __builtin_amdgcn_mfma_f32_16x16x32_bf16(af[mi], bv[ni], acc[mi][ni], 0, 0, 0);
    }
    SBAR();                              // all waves done reading buf[cur]
    if (t + 2 < nt) stage_both(t + 2, cur);   // refill freed buffer
  }

  // epilogue: C/D layout col=lane&15, row=lq*4+reg
#pragma unroll
  for (int mi = 0; mi < MI; ++mi) {
#pragma unroll
    for (int ni = 0; ni < NI; ++ni) {
      int gn = bn + wc + ni * 16 + lrow;
      float bvs = J.bias[gn];
      int gm0 = bm + wr + mi * 16 + lq * 4;
      if (J.Cf) {
#pragma unroll
        for (int r = 0; r < 4; ++r)
          J.Cf[(size_t)(gm0 + r) * 512 + gn] = fmaxf(acc[mi][ni][r] + bvs, 0.f);
      } else {
#pragma unroll
        for (int r = 0; r < 4; ++r)
          J.Cb[(size_t)(gm0 + r) * 512 + gn] = f2bf(acc[mi][ni][r] + bvs);
      }
    }
  }
}

// ==== fused scores + separable softmax + ctx weighted sums =================
// Per block (b, lc): 4 waves compute 32 l-rows of both 36-way softmaxes into
// LDS, then all 256 threads do the two V weighted sums, writing bf16 swz.
__global__ __launch_bounds__(256) void attn_fused(
    const unsigned short* __restrict__ qh, const unsigned short* __restrict__ s_key,
    const unsigned short* __restrict__ t_key, const unsigned short* __restrict__ s_val,
    const unsigned short* __restrict__ t_val, unsigned short* __restrict__ s_ctx,
    unsigned short* __restrict__ t_ctx) {
  __shared__ float wlT[2][36][32];   // [mat][j][l], 9.2 KB
  int b = blockIdx.x, lc = blockIdx.y;
  int tid = threadIdx.x, wave = tid >> 6, lane = tid & 63;
  int lrow = lane & 15, lq = lane >> 4;
  int mat = wave >> 1, rh = wave & 1;
  int row0 = b * 128 + lc * 32 + rh * 16;
  const unsigned short* qp = qh + (size_t)row0 * 512;
  const unsigned short* key = (mat ? s_key : t_key) + (size_t)b * 36 * 512;
  f32x4 acc[3] = {};
  for (int kc = 0; kc < 16; ++kc) {
    int k = kc * 32 + lq * 8;
    bf16x8 af = *(const bf16x8*)(qp + (size_t)lrow * 512 + k);
#pragma unroll
    for (int nf = 0; nf < 3; ++nf) {
      int n = nf * 16 + lrow; if (n > 35) n = 35;   // clamp; masked in softmax
      bf16x8 bv = *(const bf16x8*)(key + (size_t)n * 512 + k);
      acc[nf] = __builtin_amdgcn_mfma_f32_16x16x32_bf16(af, bv, acc[nf], 0, 0, 0);
    }
  }
  const float ccs = 0.022097086912079608f;   // 0.5 / sqrt(512)
  float ex[3][4];
#pragma unroll
  for (int r = 0; r < 4; ++r) {
    float a0 = acc[0][r] * ccs;
    float a1 = acc[1][r] * ccs;
    float a2 = (lrow < 4) ? acc[2][r] * ccs : -1e30f;
    float mx = fmaxf(fmaxf(a0, a1), a2);
    for (int s = 1; s < 16; s <<= 1) mx = fmaxf(mx, __shfl_xor(mx, s));
    float e0 = __expf(a0 - mx), e1 = __expf(a1 - mx);
    float e2 = (lrow < 4) ? __expf(a2 - mx) : 0.f;
    float sum = e0 + e1 + e2;
    for (int s = 1; s < 16; s <<= 1) sum += __shfl_xor(sum, s);
    float inv = 1.f / sum;
    ex[0][r] = e0 * inv; ex[1][r] = e1 * inv; ex[2][r] = e2 * inv;
  }
#pragma unroll
  for (int nf = 0; nf < 3; ++nf) {
    int col = nf * 16 + lrow;
    if (col < 36) {
#pragma unroll
      for (int r = 0; r < 4; ++r)
        wlT[mat][col][rh * 16 + lq * 4 + r] = ex[nf][r];
    }
  }
  __syncthreads();

  // ctx phase: thread (lgrp, hgrp) accumulates 8 l-rows x 8 h for both mats
  int lgrp = tid >> 6, hgrp = tid & 63;
  int kg = hgrp >> 3, kb = hgrp & 7;
#pragma unroll
  for (int m = 0; m < 2; ++m) {
    const unsigned short* V = (m ? t_val : s_val) + (size_t)b * 36 * 512;
    unsigned short* C = (m ? t_ctx : s_ctx);
    float a2[8][8] = {};
    for (int j = 0; j < 36; ++j) {
      f32x4 wa = *(const f32x4*)&wlT[m][j][lgrp * 8];       // broadcast
      f32x4 wb = *(const f32x4*)&wlT[m][j][lgrp * 8 + 4];
      bf16x8 v = *(const bf16x8*)(V + (size_t)j * 512 + hgrp * 8);
      float vf[8];
#pragma unroll
      for (int hi = 0; hi < 8; ++hi) vf[hi] = bf2f((unsigned short)v[hi]);
#pragma unroll
      for (int li = 0; li < 4; ++li)
#pragma unroll
        for (int hi = 0; hi < 8; ++hi) a2[li][hi] += wa[li] * vf[hi];
#pragma unroll
      for (int li = 0; li < 4; ++li)
#pragma unroll
        for (int hi = 0; hi < 8; ++hi) a2[4 + li][hi] += wb[li] * vf[hi];
    }
#pragma unroll
    for (int li = 0; li < 8; ++li) {
      int R = b * 128 + lc * 32 + lgrp * 8 + li;
      int kswz = kg * 64 + ((kb + R) & 7) * 8;
      bf16x8 o;
#pragma unroll
      for (int hi = 0; hi < 8; ++hi) o[hi] = (short)f2bf(a2[li][hi]);
      *(bf16x8*)(C + (size_t)R * 512 + kswz) = o;
    }
  }
}

// ---------------------------------------------------------------------------
extern "C" void kernel_launch(void* const* d_in, const int* in_sizes, int n_in,
                              void* d_out, int out_size, void* d_ws, size_t ws_size,
                              hipStream_t stream) {
  (void)in_sizes; (void)n_in; (void)out_size; (void)ws_size;
  const float* query = (const float*)d_in[0];
  const float* src   = (const float*)d_in[1];
  const float* trg   = (const float*)d_in[2];
  const float* Wq  = (const float*)d_in[3];  const float* bq  = (const float*)d_in[4];
  const float* Wsk = (const float*)d_in[5];  const float* bs  = (const float*)d_in[6];
  const float* Wtk = (const float*)d_in[7];  const float* bt  = (const float*)d_in[8];
  const float* Wsv = (const float*)d_in[9];  const float* bsv = (const float*)d_in[10];
  const float* Wtv = (const float*)d_in[11]; const float* btv = (const float*)d_in[12];
  const float* Wo  = (const float*)d_in[13]; const float* bo  = (const float*)d_in[14];

  // workspace (all bf16 shorts) ~42 MB
  unsigned short* WqT  = (unsigned short*)d_ws;       // 512*512
  unsigned short* WsT  = WqT  + 512 * 512;            // 512*2048 each
  unsigned short* WtT  = WsT  + 512 * 2048;
  unsigned short* WsvT = WtT  + 512 * 2048;
  unsigned short* WtvT = WsvT + 512 * 2048;
  unsigned short* WoT  = WtvT + 512 * 2048;           // 512*1536
  unsigned short* queryB = WoT + 512 * 1536;          // 4096*512 swz
  unsigned short* srcB   = queryB + 4096 * 512;       // 1152*2048 swz
  unsigned short* trgB   = srcB + 1152 * 2048;
  unsigned short* qh     = trgB + 1152 * 2048;        // 4096*512 (unswz)
  unsigned short* s_key  = qh + 4096 * 512;           // 1152*512 (unswz)
  unsigned short* t_key  = s_key + 1152 * 512;
  unsigned short* s_val  = t_key + 1152 * 512;
  unsigned short* t_val  = s_val + 1152 * 512;
  unsigned short* s_ctx  = t_val + 1152 * 512;        // 4096*512 swz
  unsigned short* t_ctx  = s_ctx + 4096 * 512;
  float* out = (float*)d_out;

  // 1. prep: 6 weight transposes (64x64 tiles) + 3 activation converts
  PrepJobs pj;
  const float* psrc[9] = { Wq, Wsk, Wtk, Wsv, Wtv, Wo, query, src, trg };
  unsigned short* pdst[9] = { WqT, WsT, WtT, WsvT, WtvT, WoT, queryB, srcB, trgB };
  int pK[9]    = { 512, 2048, 2048, 2048, 2048, 1536, 512, 2048, 2048 };
  int ptype[9] = { 0, 0, 0, 0, 0, 0, 1, 1, 1 };
  int prows[9] = { 0, 0, 0, 0, 0, 0, 4096, 1152, 1152 };
  int pbase = 0;
  for (int i = 0; i < 9; ++i) {
    pj.src[i] = psrc[i]; pj.dst[i] = pdst[i]; pj.K[i] = pK[i]; pj.type[i] = ptype[i];
    pj.base[i] = pbase;
    pbase += ptype[i] ? (prows[i] / 64) * (pK[i] / 64) : (pK[i] / 64) * 8;
  }
  prep<<<pbase, 256, 0, stream>>>(pj);

  // 2. merged projections, BM=64/BN=64: 4x(18x8) + 64x8 = 1088 blocks (4.25/CU)
  {
    GBatch pb;
    const unsigned short* Aarr[5] = { srcB, trgB, srcB, trgB, queryB };
    const unsigned short* Barr[5] = { WsT, WtT, WsvT, WtvT, WqT };
    const float* biasArr[5] = { bs, bt, bsv, btv, bq };
    unsigned short* Carr[5] = { s_key, t_key, s_val, t_val, qh };
    int base = 0;
    for (int i = 0; i < 5; ++i) {
      GJob& j = pb.j[i];
      j.A0 = Aarr[i]; j.A1 = Aarr[i]; j.A2 = Aarr[i];
      j.Bt = Barr[i]; j.bias = biasArr[i]; j.Cb = Carr[i]; j.Cf = nullptr;
      if (i < 4) { j.Astride = 2048; j.Ktot = 2048; j.lgSteps = 5; }
      else       { j.Astride = 512;  j.Ktot = 512;  j.lgSteps = 3; }
      j.tileBase = base;
      base += ((i < 4 ? 1152 : 4096) / 64) * 8;   // NT = 8 at BN=64
    }
    pb.njobs = 5;
    gemm_pipe<2, 2><<<base, 256, 0, stream>>>(pb);   // 1088 blocks (div by 8)
  }

  // 3. fused scores + softmax + ctx (128 blocks)
  attn_fused<<<dim3(32, 4), 256, 0, stream>>>(qh, s_key, t_key, s_val, t_val,
                                              s_ctx, t_ctx);

  // 4. output GEMM, BM=64/BN=64 -> 512 blocks (2/CU), f32+ReLU
  {
    GBatch ob;
    GJob& j = ob.j[0];
    j.A0 = queryB; j.A1 = s_ctx; j.A2 = t_ctx;
    j.Bt = WoT; j.bias = bo; j.Cb = nullptr; j.Cf = out;
    j.Astride = 512; j.Ktot = 1536; j.lgSteps = 3;
    j.tileBase = 0;
    for (int i = 1; i < 5; ++i) { ob.j[i] = j; ob.j[i].tileBase = 0x7fffffff; }
    ob.njobs = 1;
    gemm_pipe<2, 2><<<(4096 / 64) * 8, 256, 0, stream>>>(ob);   // 512 blocks
  }
}

// Round 8
// 94.974 us; speedup vs baseline: 1.1726x; 1.1726x over previous
//
#include <hip/hip_runtime.h>
#include <hip/hip_bf16.h>
#include <math.h>

#define DEVI __device__ __forceinline__

typedef __attribute__((ext_vector_type(4))) float f32x4;
typedef __attribute__((ext_vector_type(8))) short bf16x8;

DEVI unsigned short f2bf(float f) {
  union { float f; unsigned int u; } v; v.f = f;
  return (unsigned short)((v.u + 0x7FFFu + ((v.u >> 16) & 1u)) >> 16);
}
DEVI float bf2f(unsigned short s) {
  union { unsigned int u; float f; } v; v.u = ((unsigned int)s) << 16; return v.f;
}
DEVI bf16x8 pack8(f32x4 a, f32x4 b) {
  bf16x8 r;
  r[0] = (short)f2bf(a[0]); r[1] = (short)f2bf(a[1]);
  r[2] = (short)f2bf(a[2]); r[3] = (short)f2bf(a[3]);
  r[4] = (short)f2bf(b[0]); r[5] = (short)f2bf(b[1]);
  r[6] = (short)f2bf(b[2]); r[7] = (short)f2bf(b[3]);
  return r;
}
DEVI void gload16(const unsigned short* g, unsigned short* l) {
  __builtin_amdgcn_global_load_lds(
      (const __attribute__((address_space(1))) unsigned int*)g,
      (__attribute__((address_space(3))) unsigned int*)l, 16, 0, 0);
}
// raw workgroup barrier WITHOUT the implicit vmcnt(0) drain of __syncthreads
#define SBAR() do { asm volatile("" ::: "memory"); \
                    __builtin_amdgcn_s_barrier();  \
                    asm volatile("" ::: "memory"); } while (0)

// ==== prep: weights f32[K][512] -> bf16 [512][K] swz ; acts f32[M][K] -> bf16 [M][K] swz
// swizzle: within each 64-elem k-group, kblock kb of row n stored at ((kb+n)&7).
struct PrepJobs {
  const float* src[9];
  unsigned short* dst[9];
  int K[9];
  int base[9];
  int type[9];   // 0 = weight transpose (64x64 tiles), 1 = activation convert
};

__global__ __launch_bounds__(256) void prep(PrepJobs J) {
  __shared__ float t[64][65];   // 16.6 KB
  int tile = blockIdx.x;
  int job = 0;
  while (job < 8 && tile >= J.base[job + 1]) ++job;
  int tl = tile - J.base[job];
  int K = J.K[job];
  if (J.type[job] == 0) {
    int tn = tl & 7, tk = tl >> 3;   // 512/64 = 8 n-tiles
    int x = threadIdx.x & 63, y = threadIdx.x >> 6;
    const float* s = J.src[job];
    int k0 = tk * 64, n0 = tn * 64;
#pragma unroll
    for (int yy = y; yy < 64; yy += 4)
      t[yy][x] = s[(size_t)(k0 + yy) * 512 + n0 + x];
    __syncthreads();
    unsigned short* d = J.dst[job];
    int kb = (x >> 3) & 7, ko = x & 7;   // k = k0 + x, k0 % 64 == 0
#pragma unroll
    for (int yy = y; yy < 64; yy += 4) {
      int n = n0 + yy;
      int kswz = k0 + (((kb + n) & 7) << 3) + ko;
      d[(size_t)n * K + kswz] = f2bf(t[x][yy]);
    }
  } else {
    int nk = K >> 6;
    int rt = tl / nk;
    int r0 = rt * 64, k0 = (tl - rt * nk) * 64;
    int r = threadIdx.x >> 2, kq = threadIdx.x & 3;
    int row = r0 + r;
    const float* s = J.src[job] + (size_t)row * K + k0 + kq * 16;
    f32x4 a0 = *(const f32x4*)s;
    f32x4 a1 = *(const f32x4*)(s + 4);
    f32x4 a2 = *(const f32x4*)(s + 8);
    f32x4 a3 = *(const f32x4*)(s + 12);
    unsigned short* d = J.dst[job] + (size_t)row * K + k0;
    int kb0 = kq * 2;
    *(bf16x8*)(d + ((kb0 + row) & 7) * 8) = pack8(a0, a1);
    *(bf16x8*)(d + ((kb0 + 1 + row) & 7) * 8) = pack8(a2, a3);
  }
}

// ==== MFMA GEMM, counted-vmcnt double-buffer, templated tile ===============
// BM = MI*32, BN = NI*32, BK = 64; 4 waves (2 m x 2 n), wave tile (MI*16)x(NI*16).
// C[M][512] = concat(A0|A1|A2) @ B (+ bias). A/B bf16 pre-swizzled; staging is
// pure global_load_lds DMA; s_waitcnt vmcnt(MI+NI) keeps next tile in flight.
struct GJob {
  const unsigned short* A0; const unsigned short* A1; const unsigned short* A2;
  const unsigned short* Bt;
  const float* bias;        // may be nullptr
  unsigned short* Cb;       // bf16 out (unswizzled) ...
  float* Cf;                // ... or f32 out (no relu)
  int Astride, Bstride, nt, lgSteps, tileBase;
};
struct GBatch { GJob j[7]; int njobs; int swz; };

template <int MI, int NI>
__global__ __launch_bounds__(256) void gemm_pipe(GBatch batch) {
  constexpr int BM = MI * 32, BN = NI * 32;
  constexpr int NT = 512 / BN;            // n-tiles per job
  int gt = blockIdx.x;
  if (batch.swz) {                         // XCD swizzle only for homogeneous grids
    int cpx = gridDim.x >> 3;
    gt = (blockIdx.x & 7) * cpx + (blockIdx.x >> 3);
  }
  int job = 0;
#pragma unroll
  for (int i = 1; i < 7; ++i)
    if (i < batch.njobs && gt >= batch.j[i].tileBase) job = i;
  GJob J = batch.j[job];
  int tl = gt - J.tileBase;
  int bm = (tl / NT) * BM, bn = (tl % NT) * BN;

  __shared__ __align__(16) unsigned short La[2][BM * 64];
  __shared__ __align__(16) unsigned short Lb[2][BN * 64];

  int tid = threadIdx.x;
  int wave = tid >> 6, lane = tid & 63;
  int lrow = lane & 15, lq = lane >> 4;
  int wr = (wave >> 1) * (MI * 16), wc = (wave & 1) * (NI * 16);
  f32x4 acc[MI][NI] = {};

  int kmask = (1 << J.lgSteps) - 1;
  int nt = J.nt;

  auto stage_both = [&](int t, int buf) {
    int seg = t >> J.lgSteps;
    const unsigned short* Ab = (seg == 0) ? J.A0 : ((seg == 1) ? J.A1 : J.A2);
    const unsigned short* GA = Ab + (size_t)bm * J.Astride + (size_t)((t & kmask) << 6);
    const unsigned short* GB = J.Bt + (size_t)bn * J.Bstride + (size_t)t * 64;
#pragma unroll
    for (int p = 0; p < MI; ++p) {     // A: BM*64 bf16 = MI*256 slots of 16B
      int s = p * 256 + tid;
      gload16(GA + (size_t)(s >> 3) * J.Astride + (s & 7) * 8,
              &La[buf][(size_t)(p * 256 + wave * 64) * 8]);
    }
#pragma unroll
    for (int p = 0; p < NI; ++p) {     // B: BN*64 bf16 = NI*256 slots
      int s = p * 256 + tid;
      gload16(GB + (size_t)(s >> 3) * J.Bstride + (s & 7) * 8,
              &Lb[buf][(size_t)(p * 256 + wave * 64) * 8]);
    }
  };

  stage_both(0, 0);
  if (nt > 1) stage_both(1, 1);

  for (int t = 0; t < nt; ++t) {
    // wait until THIS tile's DMA landed; next tile's (MI+NI) stay in flight
    if (t + 1 < nt) {
      if constexpr (MI + NI == 8)      asm volatile("s_waitcnt vmcnt(8)" ::: "memory");
      else if constexpr (MI + NI == 6) asm volatile("s_waitcnt vmcnt(6)" ::: "memory");
      else                             asm volatile("s_waitcnt vmcnt(4)" ::: "memory");
    } else {
      asm volatile("s_waitcnt vmcnt(0)" ::: "memory");
    }
    SBAR();                              // all waves' tile-t data visible
    int cur = t & 1;
#pragma unroll
    for (int kc = 0; kc < 2; ++kc) {
      int kb = kc * 4 + lq;
      bf16x8 af[MI], bv[NI];
#pragma unroll
      for (int mi = 0; mi < MI; ++mi) {
        int r = wr + mi * 16 + lrow;
        af[mi] = *(const bf16x8*)&La[cur][r * 64 + ((kb + r) & 7) * 8];
      }
#pragma unroll
      for (int ni = 0; ni < NI; ++ni) {
        int r = wc + ni * 16 + lrow;
        bv[ni] = *(const bf16x8*)&Lb[cur][r * 64 + ((kb + r) & 7) * 8];
      }
#pragma unroll
      for (int mi = 0; mi < MI; ++mi)
#pragma unroll
        for (int ni = 0; ni < NI; ++ni)
          acc[mi][ni] = __builtin_amdgcn_mfma_f32_16x16x32_bf16(af[mi], bv[ni], acc[mi][ni], 0, 0, 0);
    }
    SBAR();                              // all waves done reading buf[cur]
    if (t + 2 < nt) stage_both(t + 2, cur);   // refill freed buffer
  }

  // epilogue: C/D layout col=lane&15, row=lq*4+reg
#pragma unroll
  for (int mi = 0; mi < MI; ++mi) {
#pragma unroll
    for (int ni = 0; ni < NI; ++ni) {
      int gn = bn + wc + ni * 16 + lrow;
      float bvs = J.bias ? J.bias[gn] : 0.f;
      int gm0 = bm + wr + mi * 16 + lq * 4;
      if (J.Cf) {
#pragma unroll
        for (int r = 0; r < 4; ++r)
          J.Cf[(size_t)(gm0 + r) * 512 + gn] = acc[mi][ni][r] + bvs;
      } else {
#pragma unroll
        for (int r = 0; r < 4; ++r)
          J.Cb[(size_t)(gm0 + r) * 512 + gn] = f2bf(acc[mi][ni][r] + bvs);
      }
    }
  }
}

// ==== fused scores + separable softmax + ctx weighted sums =================
__global__ __launch_bounds__(256) void attn_fused(
    const unsigned short* __restrict__ qh, const unsigned short* __restrict__ s_key,
    const unsigned short* __restrict__ t_key, const unsigned short* __restrict__ s_val,
    const unsigned short* __restrict__ t_val, unsigned short* __restrict__ s_ctx,
    unsigned short* __restrict__ t_ctx) {
  __shared__ float wlT[2][36][32];   // [mat][j][l], 9.2 KB
  int b = blockIdx.x, lc = blockIdx.y;
  int tid = threadIdx.x, wave = tid >> 6, lane = tid & 63;
  int lrow = lane & 15, lq = lane >> 4;
  int mat = wave >> 1, rh = wave & 1;
  int row0 = b * 128 + lc * 32 + rh * 16;
  const unsigned short* qp = qh + (size_t)row0 * 512;
  const unsigned short* key = (mat ? s_key : t_key) + (size_t)b * 36 * 512;
  f32x4 acc[3] = {};
  for (int kc = 0; kc < 16; ++kc) {
    int k = kc * 32 + lq * 8;
    bf16x8 af = *(const bf16x8*)(qp + (size_t)lrow * 512 + k);
#pragma unroll
    for (int nf = 0; nf < 3; ++nf) {
      int n = nf * 16 + lrow; if (n > 35) n = 35;   // clamp; masked in softmax
      bf16x8 bv = *(const bf16x8*)(key + (size_t)n * 512 + k);
      acc[nf] = __builtin_amdgcn_mfma_f32_16x16x32_bf16(af, bv, acc[nf], 0, 0, 0);
    }
  }
  const float ccs = 0.022097086912079608f;   // 0.5 / sqrt(512)
  float ex[3][4];
#pragma unroll
  for (int r = 0; r < 4; ++r) {
    float a0 = acc[0][r] * ccs;
    float a1 = acc[1][r] * ccs;
    float a2 = (lrow < 4) ? acc[2][r] * ccs : -1e30f;
    float mx = fmaxf(fmaxf(a0, a1), a2);
    for (int s = 1; s < 16; s <<= 1) mx = fmaxf(mx, __shfl_xor(mx, s));
    float e0 = __expf(a0 - mx), e1 = __expf(a1 - mx);
    float e2 = (lrow < 4) ? __expf(a2 - mx) : 0.f;
    float sum = e0 + e1 + e2;
    for (int s = 1; s < 16; s <<= 1) sum += __shfl_xor(sum, s);
    float inv = 1.f / sum;
    ex[0][r] = e0 * inv; ex[1][r] = e1 * inv; ex[2][r] = e2 * inv;
  }
#pragma unroll
  for (int nf = 0; nf < 3; ++nf) {
    int col = nf * 16 + lrow;
    if (col < 36) {
#pragma unroll
      for (int r = 0; r < 4; ++r)
        wlT[mat][col][rh * 16 + lq * 4 + r] = ex[nf][r];
    }
  }
  __syncthreads();

  // ctx phase: thread (lgrp, hgrp) accumulates 8 l-rows x 8 h for both mats
  int lgrp = tid >> 6, hgrp = tid & 63;
  int kg = hgrp >> 3, kb = hgrp & 7;
#pragma unroll
  for (int m = 0; m < 2; ++m) {
    const unsigned short* V = (m ? t_val : s_val) + (size_t)b * 36 * 512;
    unsigned short* C = (m ? t_ctx : s_ctx);
    float a2[8][8] = {};
    for (int j = 0; j < 36; ++j) {
      f32x4 wa = *(const f32x4*)&wlT[m][j][lgrp * 8];       // broadcast
      f32x4 wb = *(const f32x4*)&wlT[m][j][lgrp * 8 + 4];
      bf16x8 v = *(const bf16x8*)(V + (size_t)j * 512 + hgrp * 8);
      float vf[8];
#pragma unroll
      for (int hi = 0; hi < 8; ++hi) vf[hi] = bf2f((unsigned short)v[hi]);
#pragma unroll
      for (int li = 0; li < 4; ++li)
#pragma unroll
        for (int hi = 0; hi < 8; ++hi) a2[li][hi] += wa[li] * vf[hi];
#pragma unroll
      for (int li = 0; li < 4; ++li)
#pragma unroll
        for (int hi = 0; hi < 8; ++hi) a2[4 + li][hi] += wb[li] * vf[hi];
    }
#pragma unroll
    for (int li = 0; li < 8; ++li) {
      int R = b * 128 + lc * 32 + lgrp * 8 + li;
      int kswz = kg * 64 + ((kb + R) & 7) * 8;
      bf16x8 o;
#pragma unroll
      for (int hi = 0; hi < 8; ++hi) o[hi] = (short)f2bf(a2[li][hi]);
      *(bf16x8*)(C + (size_t)R * 512 + kswz) = o;
    }
  }
}

// ==== combine: out = relu(P + c1 + c2), 8 elems/thread =====================
__global__ __launch_bounds__(256) void combine(
    const float* __restrict__ P, const unsigned short* __restrict__ c1,
    const unsigned short* __restrict__ c2, float* __restrict__ out) {
  size_t i = ((size_t)blockIdx.x * 256 + threadIdx.x) * 8;
  bf16x8 a = *(const bf16x8*)(c1 + i);
  bf16x8 b = *(const bf16x8*)(c2 + i);
  f32x4 p0 = *(const f32x4*)(P + i);
  f32x4 p1 = *(const f32x4*)(P + i + 4);
  f32x4 o0, o1;
#pragma unroll
  for (int j = 0; j < 4; ++j) {
    o0[j] = fmaxf(p0[j] + bf2f((unsigned short)a[j]) + bf2f((unsigned short)b[j]), 0.f);
    o1[j] = fmaxf(p1[j] + bf2f((unsigned short)a[4 + j]) + bf2f((unsigned short)b[4 + j]), 0.f);
  }
  *(f32x4*)(out + i) = o0;
  *(f32x4*)(out + i + 4) = o1;
}

// ---------------------------------------------------------------------------
extern "C" void kernel_launch(void* const* d_in, const int* in_sizes, int n_in,
                              void* d_out, int out_size, void* d_ws, size_t ws_size,
                              hipStream_t stream) {
  (void)in_sizes; (void)n_in; (void)out_size; (void)ws_size;
  const float* query = (const float*)d_in[0];
  const float* src   = (const float*)d_in[1];
  const float* trg   = (const float*)d_in[2];
  const float* Wq  = (const float*)d_in[3];  const float* bq  = (const float*)d_in[4];
  const float* Wsk = (const float*)d_in[5];  const float* bs  = (const float*)d_in[6];
  const float* Wtk = (const float*)d_in[7];  const float* bt  = (const float*)d_in[8];
  const float* Wsv = (const float*)d_in[9];  const float* bsv = (const float*)d_in[10];
  const float* Wtv = (const float*)d_in[11]; const float* btv = (const float*)d_in[12];
  const float* Wo  = (const float*)d_in[13]; const float* bo  = (const float*)d_in[14];

  // workspace (bf16 shorts unless noted) ~58 MB
  unsigned short* WqT  = (unsigned short*)d_ws;       // 512*512
  unsigned short* WsT  = WqT  + 512 * 512;            // 512*2048 each
  unsigned short* WtT  = WsT  + 512 * 2048;
  unsigned short* WsvT = WtT  + 512 * 2048;
  unsigned short* WtvT = WsvT + 512 * 2048;
  unsigned short* WoT  = WtvT + 512 * 2048;           // 512*1536
  unsigned short* queryB = WoT + 512 * 1536;          // 4096*512 swz
  unsigned short* srcB   = queryB + 4096 * 512;       // 1152*2048 swz
  unsigned short* trgB   = srcB + 1152 * 2048;
  unsigned short* qh     = trgB + 1152 * 2048;        // 4096*512 (unswz)
  unsigned short* s_key  = qh + 4096 * 512;           // 1152*512 (unswz)
  unsigned short* t_key  = s_key + 1152 * 512;
  unsigned short* s_val  = t_key + 1152 * 512;
  unsigned short* t_val  = s_val + 1152 * 512;
  unsigned short* s_ctx  = t_val + 1152 * 512;        // 4096*512 swz
  unsigned short* t_ctx  = s_ctx + 4096 * 512;
  unsigned short* c1     = t_ctx + 4096 * 512;        // 4096*512 unswz
  unsigned short* c2     = c1 + 4096 * 512;
  float* P = (float*)(c2 + 4096 * 512);               // 4096*512 f32
  float* out = (float*)d_out;

  // 1. prep: 6 weight transposes (64x64 tiles) + 3 activation converts
  PrepJobs pj;
  const float* psrc[9] = { Wq, Wsk, Wtk, Wsv, Wtv, Wo, query, src, trg };
  unsigned short* pdst[9] = { WqT, WsT, WtT, WsvT, WtvT, WoT, queryB, srcB, trgB };
  int pK[9]    = { 512, 2048, 2048, 2048, 2048, 1536, 512, 2048, 2048 };
  int ptype[9] = { 0, 0, 0, 0, 0, 0, 1, 1, 1 };
  int prows[9] = { 0, 0, 0, 0, 0, 0, 4096, 1152, 1152 };
  int pbase = 0;
  for (int i = 0; i < 9; ++i) {
    pj.src[i] = psrc[i]; pj.dst[i] = pdst[i]; pj.K[i] = pK[i]; pj.type[i] = ptype[i];
    pj.base[i] = pbase;
    pbase += ptype[i] ? (prows[i] / 64) * (pK[i] / 64) : (pK[i] / 64) * 8;
  }
  prep<<<pbase, 256, 0, stream>>>(pj);

  // 2. merged projections + q + P=query@Wo1+bo : (2,4) tiles, 800 blocks, no swz
  {
    GBatch pb;
    pb.swz = 0;
    int base = 0;
    const unsigned short* Aarr[4] = { srcB, trgB, srcB, trgB };
    const unsigned short* Barr[4] = { WsT, WtT, WsvT, WtvT };
    const float* biasArr[4] = { bs, bt, bsv, btv };
    unsigned short* Carr[4] = { s_key, t_key, s_val, t_val };
    for (int i = 0; i < 4; ++i) {             // 4 big projections, 72 tiles each
      GJob& j = pb.j[i];
      j.A0 = Aarr[i]; j.A1 = Aarr[i]; j.A2 = Aarr[i];
      j.Bt = Barr[i]; j.bias = biasArr[i]; j.Cb = Carr[i]; j.Cf = nullptr;
      j.Astride = 2048; j.Bstride = 2048; j.nt = 32; j.lgSteps = 5;
      j.tileBase = base; base += (1152 / 64) * 4;
    }
    {                                          // q projection, 256 tiles
      GJob& j = pb.j[4];
      j.A0 = queryB; j.A1 = queryB; j.A2 = queryB;
      j.Bt = WqT; j.bias = bq; j.Cb = qh; j.Cf = nullptr;
      j.Astride = 512; j.Bstride = 512; j.nt = 8; j.lgSteps = 3;
      j.tileBase = base; base += (4096 / 64) * 4;
    }
    {                                          // P = query@Wo1 + bo, 256 tiles
      GJob& j = pb.j[5];
      j.A0 = queryB; j.A1 = queryB; j.A2 = queryB;
      j.Bt = WoT; j.bias = bo; j.Cb = nullptr; j.Cf = P;
      j.Astride = 512; j.Bstride = 1536; j.nt = 8; j.lgSteps = 3;
      j.tileBase = base; base += (4096 / 64) * 4;
    }
    pb.j[6] = pb.j[5]; pb.j[6].tileBase = 0x7fffffff;
    pb.njobs = 6;
    gemm_pipe<2, 4><<<base, 256, 0, stream>>>(pb);   // 800 blocks
  }

  // 3. fused scores + softmax + ctx (128 blocks)
  attn_fused<<<dim3(32, 4), 256, 0, stream>>>(qh, s_key, t_key, s_val, t_val,
                                              s_ctx, t_ctx);

  // 4. out partial GEMMs: c1 = s_ctx@Wo2, c2 = t_ctx@Wo3 : (2,2), 1024 blocks
  {
    GBatch ob;
    ob.swz = 1;
    GJob& a = ob.j[0];
    a.A0 = s_ctx; a.A1 = s_ctx; a.A2 = s_ctx;
    a.Bt = WoT + 512; a.bias = nullptr; a.Cb = c1; a.Cf = nullptr;
    a.Astride = 512; a.Bstride = 1536; a.nt = 8; a.lgSteps = 3;
    a.tileBase = 0;
    GJob& b = ob.j[1];
    b = a;
    b.A0 = t_ctx; b.A1 = t_ctx; b.A2 = t_ctx;
    b.Bt = WoT + 1024; b.Cb = c2;
    b.tileBase = (4096 / 64) * 8;              // 512
    for (int i = 2; i < 7; ++i) { ob.j[i] = b; ob.j[i].tileBase = 0x7fffffff; }
    ob.njobs = 2;
    gemm_pipe<2, 2><<<(4096 / 64) * 8 * 2, 256, 0, stream>>>(ob);   // 1024 blocks
  }

  // 5. combine: out = relu(P + c1 + c2)  (1024 blocks)
  combine<<<(4096 * 512) / (256 * 8), 256, 0, stream>>>(P, c1, c2, out);
}